// Round 1
// baseline (579.650 us; speedup 1.0000x reference)
//
#include <hip/hip_runtime.h>
#include <math.h>

#define DIMW 50
#define DWPE 5
#define CCH 230
#define REL 53
#define BAG 1024
#define SLEN 128
#define KTOT 180      // WIN * (50+5+5)
#define CP 256        // padded channels
#define LP 132        // padded length stride (float4-aligned rows, conflict-free-ish writes)
#define LOUT 126

// workspace layout (float offsets)
#define WS_WC 0                   // 180*256 combined conv weight, [k][ch]
#define WS_BSUM (KTOT*CP)         // 256
#define WS_V (WS_BSUM + 256)      // 256: attW @ MR[:,rel]
#define WS_SCORES (WS_V + 256)    // 1024

// ---------------- prep: pack Wc[k][ch] (zero-padded to 256 ch) and bsum ----------------
__global__ void prep_kernel(const float* __restrict__ Wv, const float* __restrict__ Wp1,
                            const float* __restrict__ Wp2, const float* __restrict__ bv,
                            const float* __restrict__ bp1, const float* __restrict__ bp2,
                            float* __restrict__ ws) {
    int idx = blockIdx.x * 256 + threadIdx.x;
    if (idx < KTOT * CP) {
        int k = idx >> 8, ch = idx & 255;
        float v = 0.f;
        if (ch < CCH) {
            int j = k / 60;
            int d = k - j * 60;
            if (d < 50)      v = Wv[(j * 50 + d) * CCH + ch];
            else if (d < 55) v = Wp1[(j * 5 + (d - 50)) * CCH + ch];
            else             v = Wp2[(j * 5 + (d - 55)) * CCH + ch];
        }
        ws[WS_WC + idx] = v;
    } else if (idx < KTOT * CP + 256) {
        int ch = idx - KTOT * CP;
        float v = 0.f;
        if (ch < CCH) v = bv[ch] + bp1[ch] + bp2[ch];
        ws[WS_BSUM + ch] = v;
    }
}

// ---------------- v = attW @ MR[:, rel]  (230 dots of length 230) ----------------
__global__ void attv_kernel(const float* __restrict__ attW, const float* __restrict__ MR,
                            const int* __restrict__ relp, float* __restrict__ ws) {
    int i = threadIdx.x;
    int rel = *relp;
    if (i < CCH) {
        float s = 0.f;
        for (int j = 0; j < CCH; ++j) s += attW[i * CCH + j] * MR[j * REL + rel];
        ws[WS_V + i] = s;
    }
}

// ---------------- fused gather + conv + maxpool + tanh: one block per sentence ----------------
__global__ __launch_bounds__(256) void conv_kernel(
    const int* __restrict__ sen, const int* __restrict__ p1, const int* __restrict__ p2,
    const float* __restrict__ wordVec, const float* __restrict__ posVec1,
    const float* __restrict__ posVec2, const float* __restrict__ ws,
    float* __restrict__ cnn_out) {
    __shared__ float smem[60 * LP];   // xsT[d][l], later reused as 16x256 max-reduce buffer
    __shared__ int s_idx[3][SLEN];
    const int b = blockIdx.x;
    const int tid = threadIdx.x;

    if (tid < SLEN) {
        s_idx[0][tid] = sen[b * SLEN + tid];
        s_idx[1][tid] = p1[b * SLEN + tid];
        s_idx[2][tid] = p2[b * SLEN + tid];
    }
    __syncthreads();

    // gather embeddings -> LDS transposed x[l][d] -> xsT[d][l]
    for (int e = tid; e < SLEN * 60; e += 256) {
        int l = e / 60;
        int d = e - l * 60;
        float v;
        if (d < 50)      v = wordVec[s_idx[0][l] * 50 + d];
        else if (d < 55) v = posVec1[s_idx[1][l] * 5 + (d - 50)];
        else             v = posVec2[s_idx[2][l] * 5 + (d - 55)];
        smem[d * LP + l] = v;
    }
    // zero pad columns l = 128..131 (rows 128,129 read when computing padded l=126,127)
    for (int e = tid; e < 60 * 4; e += 256) {
        int d = e >> 2, l = SLEN + (e & 3);
        smem[d * LP + l] = 0.f;
    }
    __syncthreads();

    const int tc = tid & 15;          // channel group: ch0 = tc*16
    const int tl = tid >> 4;          // l group: l0 = tl*8
    const int ch0 = tc * 16;
    const int l0 = tl * 8;
    const float* Wc = ws + WS_WC;

    float4 acc[8][4];
    #pragma unroll
    for (int i = 0; i < 8; ++i)
        #pragma unroll
        for (int q = 0; q < 4; ++q) acc[i][q] = make_float4(0.f, 0.f, 0.f, 0.f);

    #pragma unroll
    for (int j = 0; j < 3; ++j) {
        #pragma unroll 2
        for (int d = 0; d < 60; ++d) {
            const float* Ar = &smem[d * LP + l0 + j];
            const float4* Bp = reinterpret_cast<const float4*>(Wc + (j * 60 + d) * CP + ch0);
            float4 bb0 = Bp[0], bb1 = Bp[1], bb2 = Bp[2], bb3 = Bp[3];
            float a[8];
            #pragma unroll
            for (int i = 0; i < 8; ++i) a[i] = Ar[i];
            #pragma unroll
            for (int i = 0; i < 8; ++i) {
                acc[i][0].x += a[i] * bb0.x; acc[i][0].y += a[i] * bb0.y;
                acc[i][0].z += a[i] * bb0.z; acc[i][0].w += a[i] * bb0.w;
                acc[i][1].x += a[i] * bb1.x; acc[i][1].y += a[i] * bb1.y;
                acc[i][1].z += a[i] * bb1.z; acc[i][1].w += a[i] * bb1.w;
                acc[i][2].x += a[i] * bb2.x; acc[i][2].y += a[i] * bb2.y;
                acc[i][2].z += a[i] * bb2.z; acc[i][2].w += a[i] * bb2.w;
                acc[i][3].x += a[i] * bb3.x; acc[i][3].y += a[i] * bb3.y;
                acc[i][3].z += a[i] * bb3.z; acc[i][3].w += a[i] * bb3.w;
            }
        }
    }

    // per-thread max over valid l (l0+i < 126); bias hoisted past max (const per channel)
    float m[16];
    #pragma unroll
    for (int n = 0; n < 16; ++n) m[n] = -3.0e38f;
    #pragma unroll
    for (int i = 0; i < 8; ++i) {
        if (l0 + i < LOUT) {
            #pragma unroll
            for (int q = 0; q < 4; ++q) {
                m[q * 4 + 0] = fmaxf(m[q * 4 + 0], acc[i][q].x);
                m[q * 4 + 1] = fmaxf(m[q * 4 + 1], acc[i][q].y);
                m[q * 4 + 2] = fmaxf(m[q * 4 + 2], acc[i][q].z);
                m[q * 4 + 3] = fmaxf(m[q * 4 + 3], acc[i][q].w);
            }
        }
    }
    __syncthreads();   // done reading xsT; reuse smem as reduce buffer [16][256]
    #pragma unroll
    for (int q = 0; q < 4; ++q) {
        float4 mv = make_float4(m[q * 4 + 0], m[q * 4 + 1], m[q * 4 + 2], m[q * 4 + 3]);
        *reinterpret_cast<float4*>(&smem[tl * CP + ch0 + q * 4]) = mv;
    }
    __syncthreads();
    float mm = -3.0e38f;
    #pragma unroll
    for (int t = 0; t < 16; ++t) mm = fmaxf(mm, smem[t * CP + tid]);
    if (tid < CCH) {
        float bs = ws[WS_BSUM + tid];
        cnn_out[b * CCH + tid] = tanhf(mm + bs);
    }
}

// ---------------- per-sentence attention score: one wave per sentence ----------------
__global__ void scores_kernel(const float* __restrict__ cnn, const float* __restrict__ vvec,
                              const float* __restrict__ MRb, const int* __restrict__ relp,
                              float* __restrict__ scores) {
    int b = blockIdx.x, lane = threadIdx.x;
    float s = 0.f;
    for (int c = lane; c < CCH; c += 64) s += cnn[b * CCH + c] * vvec[c];
    for (int off = 32; off > 0; off >>= 1) s += __shfl_down(s, off, 64);
    if (lane == 0) scores[b] = s + MRb[*relp];
}

// ---------------- bag softmax + weighted sum + final logits softmax ----------------
__global__ void final_kernel(const float* __restrict__ cnn, const float* __restrict__ MR,
                             const float* __restrict__ MRb, const float* __restrict__ scores,
                             float* __restrict__ out0, float* __restrict__ att_out,
                             float* __restrict__ w_out) {
    __shared__ float red[1024];
    __shared__ float wbuf[1024];
    __shared__ float abuf[256];
    __shared__ float lbuf[64];
    int tid = threadIdx.x;
    float s = scores[tid];
    red[tid] = s; __syncthreads();
    for (int off = 512; off > 0; off >>= 1) {
        if (tid < off) red[tid] = fmaxf(red[tid], red[tid + off]);
        __syncthreads();
    }
    float mx = red[0]; __syncthreads();
    float e = expf(s - mx);
    red[tid] = e; __syncthreads();
    for (int off = 512; off > 0; off >>= 1) {
        if (tid < off) red[tid] += red[tid + off];
        __syncthreads();
    }
    float sum = red[0]; __syncthreads();
    float w = e / sum;
    w_out[tid] = w;
    wbuf[tid] = w;
    __syncthreads();

    // att_output: 4 b-groups x 256 channels of partial sums
    int ch = tid & 255, grp = tid >> 8;
    float a = 0.f;
    if (ch < CCH) {
        int bb0 = grp * 256;
        for (int bb = bb0; bb < bb0 + 256; ++bb) a += wbuf[bb] * cnn[bb * CCH + ch];
    }
    red[grp * 256 + ch] = a;
    __syncthreads();
    float t = 0.f;
    if (tid < 256) {
        float att = red[tid] + red[256 + tid] + red[512 + tid] + red[768 + tid];
        if (tid < CCH) { att_out[tid] = att; abuf[tid] = att; }
    }
    __syncthreads();
    if (tid < REL) {
        t = MRb[tid];
        for (int c = 0; c < CCH; ++c) t += abuf[c] * MR[c * REL + tid];
        lbuf[tid] = t;
    }
    __syncthreads();
    if (tid == 0) {
        float m2 = -3.0e38f;
        for (int i = 0; i < REL; ++i) m2 = fmaxf(m2, lbuf[i]);
        float s2 = 0.f;
        for (int i = 0; i < REL; ++i) s2 += expf(lbuf[i] - m2);
        lbuf[60] = m2; lbuf[61] = s2;
    }
    __syncthreads();
    if (tid < REL) out0[tid] = expf(t - lbuf[60]) / lbuf[61];
}

extern "C" void kernel_launch(void* const* d_in, const int* in_sizes, int n_in,
                              void* d_out, int out_size, void* d_ws, size_t ws_size,
                              hipStream_t stream) {
    const int* sen = (const int*)d_in[0];
    const int* p1  = (const int*)d_in[1];
    const int* p2  = (const int*)d_in[2];
    const float* wordVec = (const float*)d_in[3];
    const float* posVec1 = (const float*)d_in[4];
    const float* posVec2 = (const float*)d_in[5];
    const float* Wv  = (const float*)d_in[6];
    const float* Wp1 = (const float*)d_in[7];
    const float* Wp2 = (const float*)d_in[8];
    const float* bv  = (const float*)d_in[9];
    const float* bp1 = (const float*)d_in[10];
    const float* bp2 = (const float*)d_in[11];
    const float* attW = (const float*)d_in[12];
    const float* MR  = (const float*)d_in[13];
    const float* MRb = (const float*)d_in[14];
    const int* relp  = (const int*)d_in[15];

    float* ws = (float*)d_ws;
    float* out = (float*)d_out;
    float* out0    = out;                      // [53]
    float* att_out = out + REL;                // [230]
    float* cnn_out = out + REL + CCH;          // [1024*230]
    float* w_out   = out + REL + CCH + BAG * CCH; // [1024]

    hipLaunchKernelGGL(prep_kernel, dim3((KTOT * CP + 256 + 255) / 256), dim3(256), 0, stream,
                       Wv, Wp1, Wp2, bv, bp1, bp2, ws);
    hipLaunchKernelGGL(attv_kernel, dim3(1), dim3(256), 0, stream, attW, MR, relp, ws);
    hipLaunchKernelGGL(conv_kernel, dim3(BAG), dim3(256), 0, stream,
                       sen, p1, p2, wordVec, posVec1, posVec2, ws, cnn_out);
    hipLaunchKernelGGL(scores_kernel, dim3(BAG), dim3(64), 0, stream,
                       cnn_out, ws + WS_V, MRb, relp, ws + WS_SCORES);
    hipLaunchKernelGGL(final_kernel, dim3(1), dim3(1024), 0, stream,
                       cnn_out, MR, MRb, ws + WS_SCORES, out0, att_out, w_out);
}

// Round 2
// 396.159 us; speedup vs baseline: 1.4632x; 1.4632x over previous
//
#include <hip/hip_runtime.h>
#include <math.h>

#define CCH 230
#define REL 53
#define BAG 1024
#define SLEN 128
#define LOUT 126
#define XROW 66
#define NELEM (130 * 64)

typedef __bf16 bf16x8 __attribute__((ext_vector_type(8)));
typedef float f32x4 __attribute__((ext_vector_type(4)));

#define WS_BF_USHORTS (16 * 6 * 64 * 8)
#define WS_BSUM 24576
#define WS_V    24832
#define WS_SCORES 25088

__device__ __forceinline__ unsigned short f2bf(float f) {
    unsigned u = __builtin_bit_cast(unsigned, f);
    unsigned r = (u + 0x7fffu + ((u >> 16) & 1u)) >> 16;
    return (unsigned short)r;
}

__global__ void prep_kernel(const float* __restrict__ Wv, const float* __restrict__ Wp1,
                            const float* __restrict__ Wp2, const float* __restrict__ bv,
                            const float* __restrict__ bp1, const float* __restrict__ bp2,
                            float* __restrict__ ws) {
    int idx = blockIdx.x * 256 + threadIdx.x;
    if (idx < WS_BF_USHORTS) {
        int j = idx & 7;
        int lane = (idx >> 3) & 63;
        int q = idx >> 9;
        int ks = q % 6, ntile = q / 6;
        int n = ntile * 16 + (lane & 15);
        int k = ks * 32 + (lane >> 4) * 8 + j;
        float v = 0.f;
        if (k < 180 && n < CCH) {
            int jw = k / 60;
            int d = k - jw * 60;
            if (d < 50)      v = Wv[(jw * 50 + d) * CCH + n];
            else if (d < 55) v = Wp1[(jw * 5 + (d - 50)) * CCH + n];
            else             v = Wp2[(jw * 5 + (d - 55)) * CCH + n];
        }
        ((unsigned short*)ws)[idx] = f2bf(v);
    } else if (idx < WS_BF_USHORTS + 256) {
        int ch = idx - WS_BF_USHORTS;
        float v = 0.f;
        if (ch < CCH) v = bv[ch] + bp1[ch] + bp2[ch];
        ws[WS_BSUM + ch] = v;
    }
}

__global__ void attv_kernel(const float* __restrict__ attW, const float* __restrict__ MR,
                            const int* __restrict__ relp, float* __restrict__ ws) {
    int i = blockIdx.x, lane = threadIdx.x;
    int rel = *relp;
    float s = 0.f;
    for (int j = lane; j < CCH; j += 64) s += attW[i * CCH + j] * MR[j * REL + rel];
    for (int off = 32; off > 0; off >>= 1) s += __shfl_down(s, off, 64);
    if (lane == 0) ws[WS_V + i] = s;
}

__global__ __launch_bounds__(256, 2) void conv_kernel(
    const int* __restrict__ sen, const int* __restrict__ p1, const int* __restrict__ p2,
    const float* __restrict__ wordVec, const float* __restrict__ posVec1,
    const float* __restrict__ posVec2, const float* __restrict__ ws,
    const float* __restrict__ MRb, const int* __restrict__ relp,
    float* __restrict__ cnn_out, float* __restrict__ scores) {
    __shared__ unsigned short x_lds[130 * XROW];
    __shared__ __align__(16) unsigned short a_lds[24 * 128 * 8];
    __shared__ int s_idx[3][SLEN];
    __shared__ float s_red[4];
    const int b = blockIdx.x;
    const int tid = threadIdx.x;

    if (tid < SLEN) {
        s_idx[0][tid] = sen[b * SLEN + tid];
        s_idx[1][tid] = p1[b * SLEN + tid];
        s_idx[2][tid] = p2[b * SLEN + tid];
    }
    __syncthreads();

    for (int e0 = tid; e0 < NELEM; e0 += 2048) {
        float v[8];
        #pragma unroll
        for (int u = 0; u < 8; ++u) {
            int e = e0 + u * 256;
            v[u] = 0.f;
            if (e < NELEM) {
                int l = e >> 6, d = e & 63;
                if (l < SLEN && d < 60) {
                    if (d < 50)      v[u] = wordVec[s_idx[0][l] * 50 + d];
                    else if (d < 55) v[u] = posVec1[s_idx[1][l] * 5 + (d - 50)];
                    else             v[u] = posVec2[s_idx[2][l] * 5 + (d - 55)];
                }
            }
        }
        #pragma unroll
        for (int u = 0; u < 8; ++u) {
            int e = e0 + u * 256;
            if (e < NELEM) x_lds[(e >> 6) * XROW + (e & 63)] = f2bf(v[u]);
        }
    }
    __syncthreads();

    for (int g = tid; g < 24 * 128; g += 256) {
        int kg = g >> 7, m = g & 127;
        union { unsigned short u16[8]; uint4 v4; } tmp;
        #pragma unroll
        for (int j = 0; j < 8; ++j) {
            int k = kg * 8 + j;
            unsigned short v = 0;
            if (k < 180) {
                int jw = k / 60;
                int d = k - jw * 60;
                v = x_lds[(m + jw) * XROW + d];
            }
            tmp.u16[j] = v;
        }
        int mp = m ^ (kg & 7);
        *reinterpret_cast<uint4*>(&a_lds[(kg * 128 + mp) * 8]) = tmp.v4;
    }
    __syncthreads();

    const int lane = tid & 63, w = tid >> 6;
    const int quad = lane >> 4, l16 = lane & 15;
    const unsigned short* wsu = (const unsigned short*)ws;

    f32x4 acc[8][4];
    #pragma unroll
    for (int mt = 0; mt < 8; ++mt)
        #pragma unroll
        for (int nt = 0; nt < 4; ++nt) acc[mt][nt] = (f32x4){0.f, 0.f, 0.f, 0.f};

    #pragma unroll
    for (int ks = 0; ks < 6; ++ks) {
        bf16x8 bfrag[4];
        #pragma unroll
        for (int nt = 0; nt < 4; ++nt) {
            int ntile = w * 4 + nt;
            bfrag[nt] = *reinterpret_cast<const bf16x8*>(wsu + ((ntile * 6 + ks) * 64 + lane) * 8);
        }
        int kg = ks * 4 + quad;
        int kswz = kg & 7;
        #pragma unroll
        for (int mt = 0; mt < 8; ++mt) {
            int mp = (mt * 16 + l16) ^ kswz;
            bf16x8 afrag = *reinterpret_cast<const bf16x8*>(&a_lds[(kg * 128 + mp) * 8]);
            #pragma unroll
            for (int nt = 0; nt < 4; ++nt)
                acc[mt][nt] = __builtin_amdgcn_mfma_f32_16x16x32_bf16(afrag, bfrag[nt], acc[mt][nt], 0, 0, 0);
        }
    }

    float vals[4];
    #pragma unroll
    for (int nt = 0; nt < 4; ++nt) {
        float mv = -3.0e38f;
        #pragma unroll
        for (int mt = 0; mt < 8; ++mt) {
            #pragma unroll
            for (int r = 0; r < 4; ++r) {
                int l = mt * 16 + quad * 4 + r;
                if (l < LOUT) mv = fmaxf(mv, acc[mt][nt][r]);
            }
        }
        mv = fmaxf(mv, __shfl_xor(mv, 16, 64));
        mv = fmaxf(mv, __shfl_xor(mv, 32, 64));
        int ch = w * 64 + nt * 16 + l16;
        float t = tanhf(mv + ws[WS_BSUM + ch]);
        vals[nt] = t;
        if (quad == 0 && ch < CCH) cnn_out[b * CCH + ch] = t;
    }

    float s = 0.f;
    if (quad == 0) {
        #pragma unroll
        for (int nt = 0; nt < 4; ++nt) {
            int ch = w * 64 + nt * 16 + l16;
            if (ch < CCH) s += vals[nt] * ws[WS_V + ch];
        }
    }
    for (int off = 32; off > 0; off >>= 1) s += __shfl_down(s, off, 64);
    if (lane == 0) s_red[w] = s;
    __syncthreads();
    if (tid == 0) scores[b] = s_red[0] + s_red[1] + s_red[2] + s_red[3] + MRb[*relp];
}

__global__ void final_kernel(const float* __restrict__ cnn, const float* __restrict__ MR,
                             const float* __restrict__ MRb, const float* __restrict__ scores,
                             float* __restrict__ out0, float* __restrict__ att_out,
                             float* __restrict__ w_out) {
    __shared__ float red[1024];
    __shared__ float wbuf[1024];
    __shared__ float abuf[256];
    __shared__ float lbuf[64];
    int tid = threadIdx.x;
    float s = scores[tid];
    red[tid] = s; __syncthreads();
    for (int off = 512; off > 0; off >>= 1) {
        if (tid < off) red[tid] = fmaxf(red[tid], red[tid + off]);
        __syncthreads();
    }
    float mx = red[0]; __syncthreads();
    float e = expf(s - mx);
    red[tid] = e; __syncthreads();
    for (int off = 512; off > 0; off >>= 1) {
        if (tid < off) red[tid] += red[tid + off];
        __syncthreads();
    }
    float sum = red[0]; __syncthreads();
    float w = e / sum;
    w_out[tid] = w;
    wbuf[tid] = w;
    __syncthreads();

    int ch = tid & 255, grp = tid >> 8;
    float a = 0.f;
    if (ch < CCH) {
        int bb0 = grp * 256;
        for (int bb = bb0; bb < bb0 + 256; ++bb) a += wbuf[bb] * cnn[bb * CCH + ch];
    }
    red[grp * 256 + ch] = a;
    __syncthreads();
    float t = 0.f;
    if (tid < 256) {
        float att = red[tid] + red[256 + tid] + red[512 + tid] + red[768 + tid];
        if (tid < CCH) { att_out[tid] = att; abuf[tid] = att; }
    }
    __syncthreads();
    if (tid < REL) {
        t = MRb[tid];
        for (int c = 0; c < CCH; ++c) t += abuf[c] * MR[c * REL + tid];
        lbuf[tid] = t;
    }
    __syncthreads();
    if (tid == 0) {
        float m2 = -3.0e38f;
        for (int i = 0; i < REL; ++i) m2 = fmaxf(m2, lbuf[i]);
        float s2 = 0.f;
        for (int i = 0; i < REL; ++i) s2 += expf(lbuf[i] - m2);
        lbuf[60] = m2; lbuf[61] = s2;
    }
    __syncthreads();
    if (tid < REL) out0[tid] = expf(t - lbuf[60]) / lbuf[61];
}

extern "C" void kernel_launch(void* const* d_in, const int* in_sizes, int n_in,
                              void* d_out, int out_size, void* d_ws, size_t ws_size,
                              hipStream_t stream) {
    const int* sen = (const int*)d_in[0];
    const int* p1  = (const int*)d_in[1];
    const int* p2  = (const int*)d_in[2];
    const float* wordVec = (const float*)d_in[3];
    const float* posVec1 = (const float*)d_in[4];
    const float* posVec2 = (const float*)d_in[5];
    const float* Wv  = (const float*)d_in[6];
    const float* Wp1 = (const float*)d_in[7];
    const float* Wp2 = (const float*)d_in[8];
    const float* bv  = (const float*)d_in[9];
    const float* bp1 = (const float*)d_in[10];
    const float* bp2 = (const float*)d_in[11];
    const float* attW = (const float*)d_in[12];
    const float* MR  = (const float*)d_in[13];
    const float* MRb = (const float*)d_in[14];
    const int* relp  = (const int*)d_in[15];

    float* ws = (float*)d_ws;
    float* out = (float*)d_out;
    float* out0    = out;
    float* att_out = out + REL;
    float* cnn_out = out + REL + CCH;
    float* w_out   = out + REL + CCH + BAG * CCH;

    hipLaunchKernelGGL(prep_kernel, dim3((WS_BF_USHORTS + 256 + 255) / 256), dim3(256), 0, stream,
                       Wv, Wp1, Wp2, bv, bp1, bp2, ws);
    hipLaunchKernelGGL(attv_kernel, dim3(CCH), dim3(64), 0, stream, attW, MR, relp, ws);
    hipLaunchKernelGGL(conv_kernel, dim3(BAG), dim3(256), 0, stream,
                       sen, p1, p2, wordVec, posVec1, posVec2, ws, MRb, relp,
                       cnn_out, ws + WS_SCORES);
    hipLaunchKernelGGL(final_kernel, dim3(1), dim3(1024), 0, stream,
                       cnn_out, MR, MRb, ws + WS_SCORES, out0, att_out, w_out);
}

// Round 3
// 317.547 us; speedup vs baseline: 1.8254x; 1.2476x over previous
//
#include <hip/hip_runtime.h>
#include <math.h>

#define CCH 230
#define REL 53
#define BAG 1024
#define SLEN 128
#define LOUT 126

typedef __bf16 bf16x8 __attribute__((ext_vector_type(8)));
typedef float f32x4 __attribute__((ext_vector_type(4)));

// ---- workspace layout ----
// ushort region: B fragments [ntile(16)][ks(6)][lane(64)][j(8)] = 49152 ushorts
#define WS_BF_USHORTS (16 * 6 * 64 * 8)
#define WS_BSUM 24576     // float offset: 256 bias sums
#define WS_V    24832     // float offset: 256 = attW @ MR[:,rel]
#define WS_SCORES 25088   // float offset: 1024 scores

__device__ __forceinline__ unsigned short f2bf(float f) {
    unsigned u = __builtin_bit_cast(unsigned, f);
    unsigned r = (u + 0x7fffu + ((u >> 16) & 1u)) >> 16;
    return (unsigned short)r;
}

// ---------------- prep (B fragment pack + bias) fused with attv ----------------
// blocks 0..192: pack 49408 elements; blocks 193..250: attW @ MR[:,rel], 4 rows/block
__global__ void pa_kernel(const float* __restrict__ Wv, const float* __restrict__ Wp1,
                          const float* __restrict__ Wp2, const float* __restrict__ bv,
                          const float* __restrict__ bp1, const float* __restrict__ bp2,
                          const float* __restrict__ attW, const float* __restrict__ MR,
                          const int* __restrict__ relp, float* __restrict__ ws) {
    if (blockIdx.x < 193) {
        int idx = blockIdx.x * 256 + threadIdx.x;
        if (idx < WS_BF_USHORTS) {
            int j = idx & 7;
            int lane = (idx >> 3) & 63;
            int q = idx >> 9;
            int ks = q % 6, ntile = q / 6;
            int n = ntile * 16 + (lane & 15);
            int k = ks * 32 + (lane >> 4) * 8 + j;
            float v = 0.f;
            if (k < 180 && n < CCH) {
                int jw = k / 60;
                int d = k - jw * 60;
                if (d < 50)      v = Wv[(jw * 50 + d) * CCH + n];
                else if (d < 55) v = Wp1[(jw * 5 + (d - 50)) * CCH + n];
                else             v = Wp2[(jw * 5 + (d - 55)) * CCH + n];
            }
            ((unsigned short*)ws)[idx] = f2bf(v);
        } else {
            int ch = idx - WS_BF_USHORTS;   // 0..255
            float v = 0.f;
            if (ch < CCH) v = bv[ch] + bp1[ch] + bp2[ch];
            ws[WS_BSUM + ch] = v;
        }
    } else {
        int i = (blockIdx.x - 193) * 4 + (threadIdx.x >> 6);
        int lane = threadIdx.x & 63;
        if (i < CCH) {
            int rel = *relp;
            float s = 0.f;
            for (int j = lane; j < CCH; j += 64) s += attW[i * CCH + j] * MR[j * REL + rel];
            for (int off = 32; off > 0; off >>= 1) s += __shfl_down(s, off, 64);
            if (lane == 0) ws[WS_V + i] = s;
        }
    }
}

// ---------------- fused gather + MFMA GEMM (direct im2col via stride-60 LDS) ----------------
__global__ __launch_bounds__(256, 2) void conv_kernel(
    const int* __restrict__ sen, const int* __restrict__ p1, const int* __restrict__ p2,
    const float* __restrict__ wordVec, const float* __restrict__ posVec1,
    const float* __restrict__ posVec2, const float* __restrict__ ws,
    const float* __restrict__ MRb, const int* __restrict__ relp,
    float* __restrict__ cnn_out, float* __restrict__ scores) {
    // x[l][d] bf16 rows of stride EXACTLY 60: im2col row m is contiguous at m*60+k
    __shared__ __align__(16) unsigned short x_lds[132 * 60];
    __shared__ int s_idx[3][SLEN];
    __shared__ float s_red[4];
    const int b = blockIdx.x;
    const int tid = threadIdx.x;

    if (tid < SLEN) {
        s_idx[0][tid] = sen[b * SLEN + tid];
        s_idx[1][tid] = p1[b * SLEN + tid];
        s_idx[2][tid] = p2[b * SLEN + tid];
    }
    __syncthreads();

    // gather: 4 threads per row; rows 128..131 zero-filled
    for (int slot = tid; slot < 132 * 4; slot += 256) {
        int l = slot >> 2, t = slot & 3;
        if (t < 3) {
            float v[16];
            if (l < SLEN) {
                const float* base = wordVec + s_idx[0][l] * 50 + t * 16;
                #pragma unroll
                for (int k2 = 0; k2 < 8; ++k2) {
                    float2 f = *reinterpret_cast<const float2*>(base + 2 * k2);
                    v[2 * k2] = f.x; v[2 * k2 + 1] = f.y;
                }
            } else {
                #pragma unroll
                for (int q = 0; q < 16; ++q) v[q] = 0.f;
            }
            ushort4 o[4];
            #pragma unroll
            for (int q = 0; q < 4; ++q) {
                o[q].x = f2bf(v[4 * q + 0]); o[q].y = f2bf(v[4 * q + 1]);
                o[q].z = f2bf(v[4 * q + 2]); o[q].w = f2bf(v[4 * q + 3]);
            }
            ushort4* dst = reinterpret_cast<ushort4*>(x_lds + l * 60 + t * 16);
            #pragma unroll
            for (int q = 0; q < 4; ++q) dst[q] = o[q];
        } else {
            float v[12];
            if (l < SLEN) {
                float2 wv = *reinterpret_cast<const float2*>(wordVec + s_idx[0][l] * 50 + 48);
                v[0] = wv.x; v[1] = wv.y;
                int i1 = s_idx[1][l] * 5, i2 = s_idx[2][l] * 5;
                #pragma unroll
                for (int j = 0; j < 5; ++j) { v[2 + j] = posVec1[i1 + j]; v[7 + j] = posVec2[i2 + j]; }
            } else {
                #pragma unroll
                for (int q = 0; q < 12; ++q) v[q] = 0.f;
            }
            ushort4 o[3];
            #pragma unroll
            for (int q = 0; q < 3; ++q) {
                o[q].x = f2bf(v[4 * q + 0]); o[q].y = f2bf(v[4 * q + 1]);
                o[q].z = f2bf(v[4 * q + 2]); o[q].w = f2bf(v[4 * q + 3]);
            }
            ushort4* dst = reinterpret_cast<ushort4*>(x_lds + l * 60 + 48);
            #pragma unroll
            for (int q = 0; q < 3; ++q) dst[q] = o[q];
        }
    }
    __syncthreads();

    const int lane = tid & 63, w = tid >> 6;
    const int quad = lane >> 4, l16 = lane & 15;
    const unsigned short* wsu = (const unsigned short*)ws;

    f32x4 acc[8][4];
    #pragma unroll
    for (int mt = 0; mt < 8; ++mt)
        #pragma unroll
        for (int nt = 0; nt < 4; ++nt) acc[mt][nt] = (f32x4){0.f, 0.f, 0.f, 0.f};

    union AU { uint2 u2[2]; bf16x8 v; };

    #pragma unroll
    for (int ks = 0; ks < 6; ++ks) {
        bf16x8 bfrag[4];
        #pragma unroll
        for (int nt = 0; nt < 4; ++nt) {
            int ntile = w * 4 + nt;
            bfrag[nt] = *reinterpret_cast<const bf16x8*>(wsu + ((ntile * 6 + ks) * 64 + lane) * 8);
        }
        int kg = ks * 4 + quad;          // k-group: k = kg*8 + j
        #pragma unroll
        for (int mt = 0; mt < 8; ++mt) {
            int m = mt * 16 + l16;
            const uint2* ap = reinterpret_cast<const uint2*>(x_lds + m * 60 + kg * 8);
            AU a; a.u2[0] = ap[0]; a.u2[1] = ap[1];
            #pragma unroll
            for (int nt = 0; nt < 4; ++nt)
                acc[mt][nt] = __builtin_amdgcn_mfma_f32_16x16x32_bf16(a.v, bfrag[nt], acc[mt][nt], 0, 0, 0);
        }
    }

    // epilogue: masked max over l, cross-quad reduce, bias+tanh, store, fused score
    float vals[4];
    #pragma unroll
    for (int nt = 0; nt < 4; ++nt) {
        float mv = -3.0e38f;
        #pragma unroll
        for (int mt = 0; mt < 8; ++mt) {
            #pragma unroll
            for (int r = 0; r < 4; ++r) {
                int l = mt * 16 + quad * 4 + r;
                if (l < LOUT) mv = fmaxf(mv, acc[mt][nt][r]);
            }
        }
        mv = fmaxf(mv, __shfl_xor(mv, 16, 64));
        mv = fmaxf(mv, __shfl_xor(mv, 32, 64));
        int ch = w * 64 + nt * 16 + l16;
        float t = tanhf(mv + ws[WS_BSUM + ch]);
        vals[nt] = t;
        if (quad == 0 && ch < CCH) cnn_out[b * CCH + ch] = t;
    }

    float s = 0.f;
    if (quad == 0) {
        #pragma unroll
        for (int nt = 0; nt < 4; ++nt) {
            int ch = w * 64 + nt * 16 + l16;
            if (ch < CCH) s += vals[nt] * ws[WS_V + ch];
        }
    }
    for (int off = 32; off > 0; off >>= 1) s += __shfl_down(s, off, 64);
    if (lane == 0) s_red[w] = s;
    __syncthreads();
    if (tid == 0) scores[b] = s_red[0] + s_red[1] + s_red[2] + s_red[3] + MRb[*relp];
}

// ---------------- bag softmax + weighted sum + final logits softmax ----------------
__global__ void final_kernel(const float* __restrict__ cnn, const float* __restrict__ MR,
                             const float* __restrict__ MRb, const float* __restrict__ scores,
                             float* __restrict__ out0, float* __restrict__ att_out,
                             float* __restrict__ w_out) {
    __shared__ float red[1024];
    __shared__ float wbuf[1024];
    __shared__ float abuf[256];
    __shared__ float lbuf[64];
    __shared__ float MRs[CCH * REL];   // 48760 B
    int tid = threadIdx.x;

    // stage MR into LDS (coalesced), overlapping the softmax reductions
    for (int i = tid; i < CCH * REL; i += 1024) MRs[i] = MR[i];

    float s = scores[tid];
    red[tid] = s; __syncthreads();
    for (int off = 512; off > 0; off >>= 1) {
        if (tid < off) red[tid] = fmaxf(red[tid], red[tid + off]);
        __syncthreads();
    }
    float mx = red[0]; __syncthreads();
    float e = expf(s - mx);
    red[tid] = e; __syncthreads();
    for (int off = 512; off > 0; off >>= 1) {
        if (tid < off) red[tid] += red[tid + off];
        __syncthreads();
    }
    float sum = red[0]; __syncthreads();
    float w = e / sum;
    w_out[tid] = w;
    wbuf[tid] = w;
    __syncthreads();

    // weighted sum: 4 b-groups x 256 channels, 16 loads in flight
    int ch = tid & 255, grp = tid >> 8;
    float a = 0.f;
    if (ch < CCH) {
        int bb0 = grp * 256;
        #pragma unroll 16
        for (int bb = bb0; bb < bb0 + 256; ++bb) a += wbuf[bb] * cnn[bb * CCH + ch];
    }
    red[grp * 256 + ch] = a;
    __syncthreads();
    float t = 0.f;
    if (tid < 256) {
        float att = red[tid] + red[256 + tid] + red[512 + tid] + red[768 + tid];
        if (tid < CCH) { att_out[tid] = att; abuf[tid] = att; }
    }
    __syncthreads();
    if (tid < REL) {
        t = MRb[tid];
        #pragma unroll 10
        for (int c = 0; c < CCH; ++c) t += abuf[c] * MRs[c * REL + tid];
        lbuf[tid] = t;
    }
    __syncthreads();
    if (tid == 0) {
        float m2 = -3.0e38f;
        for (int i = 0; i < REL; ++i) m2 = fmaxf(m2, lbuf[i]);
        float s2 = 0.f;
        for (int i = 0; i < REL; ++i) s2 += expf(lbuf[i] - m2);
        lbuf[60] = m2; lbuf[61] = s2;
    }
    __syncthreads();
    if (tid < REL) out0[tid] = expf(t - lbuf[60]) / lbuf[61];
}

extern "C" void kernel_launch(void* const* d_in, const int* in_sizes, int n_in,
                              void* d_out, int out_size, void* d_ws, size_t ws_size,
                              hipStream_t stream) {
    const int* sen = (const int*)d_in[0];
    const int* p1  = (const int*)d_in[1];
    const int* p2  = (const int*)d_in[2];
    const float* wordVec = (const float*)d_in[3];
    const float* posVec1 = (const float*)d_in[4];
    const float* posVec2 = (const float*)d_in[5];
    const float* Wv  = (const float*)d_in[6];
    const float* Wp1 = (const float*)d_in[7];
    const float* Wp2 = (const float*)d_in[8];
    const float* bv  = (const float*)d_in[9];
    const float* bp1 = (const float*)d_in[10];
    const float* bp2 = (const float*)d_in[11];
    const float* attW = (const float*)d_in[12];
    const float* MR  = (const float*)d_in[13];
    const float* MRb = (const float*)d_in[14];
    const int* relp  = (const int*)d_in[15];

    float* ws = (float*)d_ws;
    float* out = (float*)d_out;
    float* out0    = out;
    float* att_out = out + REL;
    float* cnn_out = out + REL + CCH;
    float* w_out   = out + REL + CCH + BAG * CCH;

    hipLaunchKernelGGL(pa_kernel, dim3(193 + 58), dim3(256), 0, stream,
                       Wv, Wp1, Wp2, bv, bp1, bp2, attW, MR, relp, ws);
    hipLaunchKernelGGL(conv_kernel, dim3(BAG), dim3(256), 0, stream,
                       sen, p1, p2, wordVec, posVec1, posVec2, ws, MRb, relp,
                       cnn_out, ws + WS_SCORES);
    hipLaunchKernelGGL(final_kernel, dim3(1), dim3(1024), 0, stream,
                       cnn_out, MR, MRb, ws + WS_SCORES, out0, att_out, w_out);
}

// Round 4
// 314.498 us; speedup vs baseline: 1.8431x; 1.0097x over previous
//
#include <hip/hip_runtime.h>
#include <math.h>

#define CCH 230
#define REL 53
#define BAG 1024
#define SLEN 128
#define LOUT 126

typedef __bf16 bf16x8 __attribute__((ext_vector_type(8)));
typedef float f32x4 __attribute__((ext_vector_type(4)));

// ---- workspace layout ----
// ushort region: B fragments [ntile(16)][ks(6)][lane(64)][j(8)] = 49152 ushorts
#define WS_BF_USHORTS (16 * 6 * 64 * 8)
#define WS_BSUM 24576     // float offset: 256 bias sums
#define WS_V    24832     // float offset: 256 = attW @ MR[:,rel]
#define WS_SCORES 25088   // float offset: 1024 scores

__device__ __forceinline__ unsigned short f2bf(float f) {
    unsigned u = __builtin_bit_cast(unsigned, f);
    unsigned r = (u + 0x7fffu + ((u >> 16) & 1u)) >> 16;
    return (unsigned short)r;
}

// ---------------- prep (B fragment pack + bias) fused with attv ----------------
__global__ void pa_kernel(const float* __restrict__ Wv, const float* __restrict__ Wp1,
                          const float* __restrict__ Wp2, const float* __restrict__ bv,
                          const float* __restrict__ bp1, const float* __restrict__ bp2,
                          const float* __restrict__ attW, const float* __restrict__ MR,
                          const int* __restrict__ relp, float* __restrict__ ws) {
    if (blockIdx.x < 193) {
        int idx = blockIdx.x * 256 + threadIdx.x;
        if (idx < WS_BF_USHORTS) {
            int j = idx & 7;
            int lane = (idx >> 3) & 63;
            int q = idx >> 9;
            int ks = q % 6, ntile = q / 6;
            int n = ntile * 16 + (lane & 15);
            int k = ks * 32 + (lane >> 4) * 8 + j;
            float v = 0.f;
            if (k < 180 && n < CCH) {
                int jw = k / 60;
                int d = k - jw * 60;
                if (d < 50)      v = Wv[(jw * 50 + d) * CCH + n];
                else if (d < 55) v = Wp1[(jw * 5 + (d - 50)) * CCH + n];
                else             v = Wp2[(jw * 5 + (d - 55)) * CCH + n];
            }
            ((unsigned short*)ws)[idx] = f2bf(v);
        } else {
            int ch = idx - WS_BF_USHORTS;
            float v = 0.f;
            if (ch < CCH) v = bv[ch] + bp1[ch] + bp2[ch];
            ws[WS_BSUM + ch] = v;
        }
    } else {
        int i = (blockIdx.x - 193) * 4 + (threadIdx.x >> 6);
        int lane = threadIdx.x & 63;
        if (i < CCH) {
            int rel = *relp;
            float s = 0.f;
            for (int j = lane; j < CCH; j += 64) s += attW[i * CCH + j] * MR[j * REL + rel];
            for (int off = 32; off > 0; off >>= 1) s += __shfl_down(s, off, 64);
            if (lane == 0) ws[WS_V + i] = s;
        }
    }
}

// ---------------- fused gather + MFMA GEMM, 512 threads, B-frags hoisted ----------------
__global__ __launch_bounds__(512, 4) void conv_kernel(
    const int* __restrict__ sen, const int* __restrict__ p1, const int* __restrict__ p2,
    const float* __restrict__ wordVec, const float* __restrict__ posVec1,
    const float* __restrict__ posVec2, const float* __restrict__ ws,
    const float* __restrict__ MRb, const int* __restrict__ relp,
    float* __restrict__ cnn_out, float* __restrict__ scores) {
    // x[l][d] bf16, row stride EXACTLY 60: im2col row m contiguous at m*60+k
    __shared__ __align__(16) unsigned short x_lds[132 * 60];
    __shared__ int s_idx[3][SLEN];
    __shared__ float s_red[8];
    const int b = blockIdx.x;
    const int tid = threadIdx.x;
    const int lane = tid & 63, w = tid >> 6;
    const int quad = lane >> 4, l16 = lane & 15;
    const unsigned short* wsu = (const unsigned short*)ws;

    // hoist ALL B-fragment loads (LDS-independent): latency hides behind gather
    bf16x8 bfrag[6][2];
    #pragma unroll
    for (int ks = 0; ks < 6; ++ks)
        #pragma unroll
        for (int nt = 0; nt < 2; ++nt) {
            int ntile = w * 2 + nt;
            bfrag[ks][nt] = *reinterpret_cast<const bf16x8*>(wsu + ((ntile * 6 + ks) * 64 + lane) * 8);
        }

    if (tid < 384) {
        int a = tid >> 7, i = tid & 127;
        const int* src = (a == 0) ? sen : (a == 1) ? p1 : p2;
        s_idx[a][i] = src[b * SLEN + i];
    }
    __syncthreads();

    // gather: one slot per thread (512 slots = 128 rows x 4)
    {
        int l = tid >> 2, t = tid & 3;
        if (t < 3) {
            float v[16];
            const float* base = wordVec + s_idx[0][l] * 50 + t * 16;
            #pragma unroll
            for (int k2 = 0; k2 < 8; ++k2) {
                float2 f = *reinterpret_cast<const float2*>(base + 2 * k2);
                v[2 * k2] = f.x; v[2 * k2 + 1] = f.y;
            }
            ushort4* dst = reinterpret_cast<ushort4*>(x_lds + l * 60 + t * 16);
            #pragma unroll
            for (int q = 0; q < 4; ++q) {
                ushort4 o;
                o.x = f2bf(v[4 * q + 0]); o.y = f2bf(v[4 * q + 1]);
                o.z = f2bf(v[4 * q + 2]); o.w = f2bf(v[4 * q + 3]);
                dst[q] = o;
            }
        } else {
            float v[12];
            float2 wv = *reinterpret_cast<const float2*>(wordVec + s_idx[0][l] * 50 + 48);
            v[0] = wv.x; v[1] = wv.y;
            int i1 = s_idx[1][l] * 5, i2 = s_idx[2][l] * 5;
            #pragma unroll
            for (int j = 0; j < 5; ++j) { v[2 + j] = posVec1[i1 + j]; v[7 + j] = posVec2[i2 + j]; }
            ushort4* dst = reinterpret_cast<ushort4*>(x_lds + l * 60 + 48);
            #pragma unroll
            for (int q = 0; q < 3; ++q) {
                ushort4 o;
                o.x = f2bf(v[4 * q + 0]); o.y = f2bf(v[4 * q + 1]);
                o.z = f2bf(v[4 * q + 2]); o.w = f2bf(v[4 * q + 3]);
                dst[q] = o;
            }
        }
    }
    // zero pad rows 128..131 (read via im2col for m=126..129 and the k-pad)
    if (tid < 16) {
        int l = SLEN + (tid >> 2), t = tid & 3;
        ushort4 z; z.x = z.y = z.z = z.w = 0;
        ushort4* dst = reinterpret_cast<ushort4*>(x_lds + l * 60 + ((t < 3) ? t * 16 : 48));
        if (t < 3) { dst[0] = z; dst[1] = z; dst[2] = z; dst[3] = z; }
        else       { dst[0] = z; dst[1] = z; dst[2] = z; }
    }
    __syncthreads();

    f32x4 acc[8][2];
    #pragma unroll
    for (int mt = 0; mt < 8; ++mt)
        #pragma unroll
        for (int nt = 0; nt < 2; ++nt) acc[mt][nt] = (f32x4){0.f, 0.f, 0.f, 0.f};

    union AU { uint2 u2[2]; bf16x8 v; };

    #pragma unroll
    for (int ks = 0; ks < 6; ++ks) {
        int kg = ks * 4 + quad;          // k = kg*8 + j
        #pragma unroll
        for (int mt = 0; mt < 8; ++mt) {
            int m = mt * 16 + l16;
            const uint2* ap = reinterpret_cast<const uint2*>(x_lds + m * 60 + kg * 8);
            AU a; a.u2[0] = ap[0]; a.u2[1] = ap[1];
            #pragma unroll
            for (int nt = 0; nt < 2; ++nt)
                acc[mt][nt] = __builtin_amdgcn_mfma_f32_16x16x32_bf16(a.v, bfrag[ks][nt], acc[mt][nt], 0, 0, 0);
        }
    }

    // epilogue: masked max over l, cross-quad reduce, bias+tanh, store, fused score
    float vals[2];
    #pragma unroll
    for (int nt = 0; nt < 2; ++nt) {
        float mv = -3.0e38f;
        #pragma unroll
        for (int mt = 0; mt < 8; ++mt) {
            #pragma unroll
            for (int r = 0; r < 4; ++r) {
                int l = mt * 16 + quad * 4 + r;
                if (l < LOUT) mv = fmaxf(mv, acc[mt][nt][r]);
            }
        }
        mv = fmaxf(mv, __shfl_xor(mv, 16, 64));
        mv = fmaxf(mv, __shfl_xor(mv, 32, 64));
        int ch = w * 32 + nt * 16 + l16;
        float t = tanhf(mv + ws[WS_BSUM + ch]);
        vals[nt] = t;
        if (quad == 0 && ch < CCH) cnn_out[b * CCH + ch] = t;
    }

    float s = 0.f;
    if (quad == 0) {
        #pragma unroll
        for (int nt = 0; nt < 2; ++nt) {
            int ch = w * 32 + nt * 16 + l16;
            if (ch < CCH) s += vals[nt] * ws[WS_V + ch];
        }
    }
    for (int off = 32; off > 0; off >>= 1) s += __shfl_down(s, off, 64);
    if (lane == 0) s_red[w] = s;
    __syncthreads();
    if (tid == 0) {
        float t = MRb[*relp];
        #pragma unroll
        for (int i = 0; i < 8; ++i) t += s_red[i];
        scores[b] = t;
    }
}

// ---------------- bag softmax + weighted sum + final logits softmax ----------------
__global__ void final_kernel(const float* __restrict__ cnn, const float* __restrict__ MR,
                             const float* __restrict__ MRb, const float* __restrict__ scores,
                             float* __restrict__ out0, float* __restrict__ att_out,
                             float* __restrict__ w_out) {
    __shared__ float red[1024];
    __shared__ float wbuf[1024];
    __shared__ float abuf[256];
    __shared__ float lbuf[64];
    __shared__ float MRs[CCH * REL];
    int tid = threadIdx.x;

    for (int i = tid; i < CCH * REL; i += 1024) MRs[i] = MR[i];

    float s = scores[tid];
    red[tid] = s; __syncthreads();
    for (int off = 512; off > 0; off >>= 1) {
        if (tid < off) red[tid] = fmaxf(red[tid], red[tid + off]);
        __syncthreads();
    }
    float mx = red[0]; __syncthreads();
    float e = expf(s - mx);
    red[tid] = e; __syncthreads();
    for (int off = 512; off > 0; off >>= 1) {
        if (tid < off) red[tid] += red[tid + off];
        __syncthreads();
    }
    float sum = red[0]; __syncthreads();
    float w = e / sum;
    w_out[tid] = w;
    wbuf[tid] = w;
    __syncthreads();

    int ch = tid & 255, grp = tid >> 8;
    float a = 0.f;
    if (ch < CCH) {
        int bb0 = grp * 256;
        #pragma unroll 16
        for (int bb = bb0; bb < bb0 + 256; ++bb) a += wbuf[bb] * cnn[bb * CCH + ch];
    }
    red[grp * 256 + ch] = a;
    __syncthreads();
    float t = 0.f;
    if (tid < 256) {
        float att = red[tid] + red[256 + tid] + red[512 + tid] + red[768 + tid];
        if (tid < CCH) { att_out[tid] = att; abuf[tid] = att; }
    }
    __syncthreads();
    if (tid < REL) {
        t = MRb[tid];
        #pragma unroll 10
        for (int c = 0; c < CCH; ++c) t += abuf[c] * MRs[c * REL + tid];
        lbuf[tid] = t;
    }
    __syncthreads();
    if (tid == 0) {
        float m2 = -3.0e38f;
        for (int i = 0; i < REL; ++i) m2 = fmaxf(m2, lbuf[i]);
        float s2 = 0.f;
        for (int i = 0; i < REL; ++i) s2 += expf(lbuf[i] - m2);
        lbuf[60] = m2; lbuf[61] = s2;
    }
    __syncthreads();
    if (tid < REL) out0[tid] = expf(t - lbuf[60]) / lbuf[61];
}

extern "C" void kernel_launch(void* const* d_in, const int* in_sizes, int n_in,
                              void* d_out, int out_size, void* d_ws, size_t ws_size,
                              hipStream_t stream) {
    const int* sen = (const int*)d_in[0];
    const int* p1  = (const int*)d_in[1];
    const int* p2  = (const int*)d_in[2];
    const float* wordVec = (const float*)d_in[3];
    const float* posVec1 = (const float*)d_in[4];
    const float* posVec2 = (const float*)d_in[5];
    const float* Wv  = (const float*)d_in[6];
    const float* Wp1 = (const float*)d_in[7];
    const float* Wp2 = (const float*)d_in[8];
    const float* bv  = (const float*)d_in[9];
    const float* bp1 = (const float*)d_in[10];
    const float* bp2 = (const float*)d_in[11];
    const float* attW = (const float*)d_in[12];
    const float* MR  = (const float*)d_in[13];
    const float* MRb = (const float*)d_in[14];
    const int* relp  = (const int*)d_in[15];

    float* ws = (float*)d_ws;
    float* out = (float*)d_out;
    float* out0    = out;
    float* att_out = out + REL;
    float* cnn_out = out + REL + CCH;
    float* w_out   = out + REL + CCH + BAG * CCH;

    hipLaunchKernelGGL(pa_kernel, dim3(193 + 58), dim3(256), 0, stream,
                       Wv, Wp1, Wp2, bv, bp1, bp2, attW, MR, relp, ws);
    hipLaunchKernelGGL(conv_kernel, dim3(BAG), dim3(512), 0, stream,
                       sen, p1, p2, wordVec, posVec1, posVec2, ws, MRb, relp,
                       cnn_out, ws + WS_SCORES);
    hipLaunchKernelGGL(final_kernel, dim3(1), dim3(1024), 0, stream,
                       cnn_out, MR, MRb, ws + WS_SCORES, out0, att_out, w_out);
}